// Round 5
// baseline (68.674 us; speedup 1.0000x reference)
//
#include <hip/hip_runtime.h>

typedef float f32x4 __attribute__((ext_vector_type(4)));
typedef short bf16x8 __attribute__((ext_vector_type(8)));

#define HW_ 1024
#define NE_ 4096
#define CHW_ 65536          // 64*1024
#define ZQ_SIZE 1048576
#define LOSS_OFF ZQ_SIZE
#define IDX_OFF (ZQ_SIZE + 1)
#define LOSS_SCALE (1.25f / 1048576.f)
#define EPS_GAP 0.125f      // on 0.5*d2 scale; covers 12-bit key truncation + split err

union FragU { unsigned u[4]; bf16x8 v; };

// split 8 f32 -> hi/lo bf16 fragments (truncation split; lo captures the tail)
__device__ __forceinline__ void split8(const float* v, FragU& hi, FragU& lo) {
#pragma unroll
    for (int p = 0; p < 4; p++) {
        float a = v[2 * p], b = v[2 * p + 1];
        unsigned ua = __float_as_uint(a), ub = __float_as_uint(b);
        hi.u[p] = (ua >> 16) | (ub & 0xFFFF0000u);
        float la = a - __uint_as_float(ua & 0xFFFF0000u);
        float lb = b - __uint_as_float(ub & 0xFFFF0000u);
        lo.u[p] = (__float_as_uint(la) >> 16) | (__float_as_uint(lb) & 0xFFFF0000u);
    }
}

// ---- kernel 1: h_e = 0.5|e|^2, h_z = 0.5|z_row|^2, init keys/loss --------
__global__ void vq_prep(const float* __restrict__ emb, const float* __restrict__ z,
                        float* __restrict__ h_e, float* __restrict__ h_z,
                        unsigned* __restrict__ k1, unsigned* __restrict__ k2,
                        float* __restrict__ out) {
    int t = blockIdx.x * 256 + threadIdx.x;   // 80*256 = 20480
    if (t < NE_) {
        const float4* er = (const float4*)(emb + (size_t)t * 64);
        float s = 0.f;
#pragma unroll
        for (int k = 0; k < 16; k++) {
            float4 e4 = er[k];
            s = fmaf(e4.x, e4.x, s); s = fmaf(e4.y, e4.y, s);
            s = fmaf(e4.z, e4.z, s); s = fmaf(e4.w, e4.w, s);
        }
        h_e[t] = 0.5f * s;
    } else {
        int n = t - NE_;                      // 0..16383
        int b = n >> 10, hw = n & 1023;
        const float* zp = z + (size_t)b * CHW_ + hw;
        float s = 0.f;
#pragma unroll
        for (int c = 0; c < 64; c++) { float v = zp[c * HW_]; s = fmaf(v, v, s); }
        h_z[n] = 0.5f * s;
        k1[n] = 0xFFFFFFFFu;
        k2[n] = 0xFFFFFFFFu;
        if (n == 0) out[LOSS_OFF] = 0.f;
    }
}

// ---- kernel 1b: precompute z bf16-split B-fragments ----------------------
// Layout: zfrag[tile(1024)][part(4: zh0,zh1,zl0,zl1)][lane(64)] x 16 B.
// Lane (lrow=l&15, lgrp=l>>4) of tile t holds channels s*32+lgrp*8+{0..7} of
// row t*16+lrow (hi split in parts 0-1, lo split in parts 2-3).
__global__ __launch_bounds__(256) void vq_zsplit(const float* __restrict__ z,
                                                 char* __restrict__ zfrag) {
    int u = blockIdx.x * 256 + threadIdx.x;   // 512*256 = 131072
    int l = u & 63;
    int s = (u >> 6) & 1;
    int t = u >> 7;                           // 0..1023
    int n = t * 16 + (l & 15);
    int b = n >> 10, hw = n & 1023;
    int c0 = s * 32 + (l >> 4) * 8;
    const float* zp = z + (size_t)b * CHW_ + hw;
    float v[8];
#pragma unroll
    for (int j = 0; j < 8; j++) v[j] = zp[(c0 + j) * HW_];
    FragU hi, lo;
    split8(v, hi, lo);
    char* base = zfrag + (size_t)t * 4096 + l * 16;
    *(FragU*)(base + s * 1024) = hi;
    *(FragU*)(base + (2 + s) * 1024) = lo;
}

// ---- kernel 2: MFMA scan -------------------------------------------------
// Grid 1024 = 16 e-chunks x 64 row-groups. Block 256 = 4 waves, 4 blocks/CU.
// Wave owns 4 e-tiles (64 e) register-resident (negated bf16-split frags).
// acc init = 0.5|z|^2 + 0.5|e|^2 ; acc += (-e).z  => acc = 0.5*d2 >= 0.
// key = (f32 bits & ~0xFFF) | e_idx ; u32 min == (score, idx) lexicographic.
__global__ __launch_bounds__(256, 4) void vq_mfma(
        const char* __restrict__ zfrag, const float* __restrict__ emb,
        const float* __restrict__ h_e, const float* __restrict__ h_z,
        unsigned* __restrict__ k1, unsigned* __restrict__ k2) {
    const int tid = threadIdx.x;
    const int lane = tid & 63;
    const int wave = tid >> 6;
    const int lrow = lane & 15;       // M/N index within tile
    const int lgrp = lane >> 4;       // k-octet group (0..3)
    const int ecb = blockIdx.x & 15;  // e-chunk (256 e)
    const int rgb = blockIdx.x >> 4;  // row-group (256 rows)

    const int ebase = ecb * 256 + wave * 64;    // wave's 64 embeddings
    const int c0 = lgrp * 8;

    // ---- load + split e-fragments (resident): 4 tiles x 2 k-steps --------
    FragU aeh[4][2], ael[4][2];
    float4 he4[4];
#pragma unroll
    for (int i = 0; i < 4; i++) {
        int eI = ebase + i * 16 + lrow;
        const float* ep = emb + (size_t)eI * 64;
#pragma unroll
        for (int s = 0; s < 2; s++) {
            float ev[8];
            const float4* e4p = (const float4*)(ep + s * 32 + c0);
            float4 ea = e4p[0], eb = e4p[1];
            ev[0] = -ea.x; ev[1] = -ea.y; ev[2] = -ea.z; ev[3] = -ea.w;
            ev[4] = -eb.x; ev[5] = -eb.y; ev[6] = -eb.z; ev[7] = -eb.w;
            split8(ev, aeh[i][s], ael[i][s]);
        }
        he4[i] = *(const float4*)(h_e + ebase + i * 16 + lgrp * 4);
    }

    // ---- scan 16 row-tiles ----------------------------------------------
    for (int rt = 0; rt < 16; rt++) {
        const int rowbase = rgb * 256 + rt * 16;
        const char* fb = zfrag + (size_t)(rgb * 16 + rt) * 4096 + lane * 16;
        bf16x8 bzh0 = *(const bf16x8*)(fb);
        bf16x8 bzh1 = *(const bf16x8*)(fb + 1024);
        bf16x8 bzl0 = *(const bf16x8*)(fb + 2048);
        bf16x8 bzl1 = *(const bf16x8*)(fb + 3072);
        const float hz = h_z[rowbase + lrow];

        unsigned s1k = 0xFFFFFFFFu, s2k = 0xFFFFFFFFu;

#pragma unroll
        for (int i = 0; i < 4; i++) {
            f32x4 acc;
            acc[0] = he4[i].x + hz; acc[1] = he4[i].y + hz;
            acc[2] = he4[i].z + hz; acc[3] = he4[i].w + hz;
            acc = __builtin_amdgcn_mfma_f32_16x16x32_bf16(aeh[i][0].v, bzh0, acc, 0, 0, 0);
            acc = __builtin_amdgcn_mfma_f32_16x16x32_bf16(aeh[i][1].v, bzh1, acc, 0, 0, 0);
            acc = __builtin_amdgcn_mfma_f32_16x16x32_bf16(ael[i][0].v, bzh0, acc, 0, 0, 0);
            acc = __builtin_amdgcn_mfma_f32_16x16x32_bf16(ael[i][1].v, bzh1, acc, 0, 0, 0);
            acc = __builtin_amdgcn_mfma_f32_16x16x32_bf16(aeh[i][0].v, bzl0, acc, 0, 0, 0);
            acc = __builtin_amdgcn_mfma_f32_16x16x32_bf16(aeh[i][1].v, bzl1, acc, 0, 0, 0);

            const unsigned eb12 = (unsigned)(ebase + i * 16 + lgrp * 4);
#pragma unroll
            for (int r = 0; r < 4; r++) {
                float sc = fmaxf(acc[r], 0.f);
                unsigned key = (__float_as_uint(sc) & 0xFFFFF000u) | (eb12 + r);
                unsigned t2 = (s1k > key) ? s1k : key;
                s2k = (s2k < t2) ? s2k : t2;
                s1k = (s1k < key) ? s1k : key;
            }
        }

        // merge across the 4 k-octet lane-groups (same z-row)
#pragma unroll
        for (int off = 16; off <= 32; off += 16) {
            unsigned o1 = (unsigned)__shfl_xor((int)s1k, off);
            unsigned o2 = (unsigned)__shfl_xor((int)s2k, off);
            unsigned t2 = (s1k > o1) ? s1k : o1;
            unsigned m2 = (s2k < o2) ? s2k : o2;
            s2k = (m2 < t2) ? m2 : t2;
            s1k = (s1k < o1) ? s1k : o1;
        }

        if (lane < 16) {
            const int n = rowbase + lane;
            unsigned old = atomicMin(&k1[n], s1k);
            unsigned disp = (old > s1k) ? old : s1k;
            atomicMin(&k2[n], disp);
            atomicMin(&k2[n], s2k);
        }
    }
}

// ---- kernel 3: outputs; 4 threads/row; exact fp64 duel for near-ties -----
__global__ __launch_bounds__(256) void vq_final(
        const float* __restrict__ z, const float* __restrict__ emb,
        const unsigned* __restrict__ k1v, const unsigned* __restrict__ k2v,
        float* __restrict__ out) {
    int t = blockIdx.x * 256 + threadIdx.x;   // 256 blocks x 256 = 65536
    int n = t >> 2;                           // row
    int q = t & 3;                            // channel quarter
    unsigned key1 = k1v[n];
    unsigned key2 = k2v[n];
    int idx = (int)(key1 & 0xFFFu);
    float s1 = __uint_as_float(key1 & 0xFFFFF000u);
    float s2 = __uint_as_float(key2 & 0xFFFFF000u);

    int b = n >> 10, hw = n & 1023;
    const float* zp = z + (size_t)b * CHW_ + hw;
    const int cq = q * 16;

    if (s2 - s1 < EPS_GAP) {                   // near-tie: exact fp64 duel
        int i2 = (int)(key2 & 0xFFFu);
        const float* ea = emb + (size_t)idx * 64 + cq;
        const float* eb = emb + (size_t)i2 * 64 + cq;
        double da = 0.0, db = 0.0;
#pragma unroll
        for (int j = 0; j < 16; j++) {
            double zv = (double)zp[(cq + j) * HW_];
            double xa = (double)ea[j] - zv;
            double xb = (double)eb[j] - zv;
            da = fma(xa, xa, da);
            db = fma(xb, xb, db);
        }
#pragma unroll
        for (int off = 1; off <= 2; off <<= 1) {
            da += __shfl_xor(da, off);
            db += __shfl_xor(db, off);
        }
        if (db < da || (db == da && i2 < idx)) idx = i2;
    }

    const float* er = emb + (size_t)idx * 64 + cq;
    float* zq = out + (size_t)b * CHW_ + hw;
    float lsum = 0.f;
#pragma unroll
    for (int j = 0; j < 16; j++) {
        float e = er[j];
        float d = e - zp[(cq + j) * HW_];
        zq[(cq + j) * HW_] = e;
        lsum = fmaf(d, d, lsum);
    }
    if (q == 0) out[IDX_OFF + n] = (float)idx;

#pragma unroll
    for (int off = 32; off; off >>= 1) lsum += __shfl_down(lsum, off);
    if ((threadIdx.x & 63) == 0) atomicAdd(&out[LOSS_OFF], lsum * LOSS_SCALE);
}

extern "C" void kernel_launch(void* const* d_in, const int* in_sizes, int n_in,
                              void* d_out, int out_size, void* d_ws, size_t ws_size,
                              hipStream_t stream) {
    const float* z   = (const float*)d_in[0];
    const float* emb = (const float*)d_in[1];
    float* out = (float*)d_out;
    char* ws = (char*)d_ws;

    float* h_e   = (float*)ws;                        // 16 KB
    float* h_z   = (float*)(ws + 16384);              // 64 KB
    unsigned* k1 = (unsigned*)(ws + 81920);           // 64 KB
    unsigned* k2 = (unsigned*)(ws + 147456);          // 64 KB
    char* zfrag  = ws + 212992;                       // 4 MB

    vq_prep  <<<80, 256, 0, stream>>>(emb, z, h_e, h_z, k1, k2, out);
    vq_zsplit<<<512, 256, 0, stream>>>(z, zfrag);
    vq_mfma  <<<1024, 256, 0, stream>>>(zfrag, emb, h_e, h_z, k1, k2);
    vq_final <<<256, 256, 0, stream>>>(z, emb, k1, k2, out);
}

// Round 6
// 67.345 us; speedup vs baseline: 1.0197x; 1.0197x over previous
//
#include <hip/hip_runtime.h>

typedef float f32x4 __attribute__((ext_vector_type(4)));
typedef short bf16x8 __attribute__((ext_vector_type(8)));

#define HW_ 1024
#define NE_ 4096
#define CHW_ 65536          // 64*1024
#define ZQ_SIZE 1048576
#define LOSS_OFF ZQ_SIZE
#define IDX_OFF (ZQ_SIZE + 1)
#define LOSS_SCALE (1.25f / 1048576.f)
#define EPS_GAP 0.15f       // on 0.5*d2 scale; covers 12-bit key trunc + split err

union FragU { unsigned u[4]; bf16x8 v; };

// split 8 f32 -> hi/lo bf16 fragments (truncation split; lo captures the tail)
__device__ __forceinline__ void split8(const float* v, FragU& hi, FragU& lo) {
#pragma unroll
    for (int p = 0; p < 4; p++) {
        float a = v[2 * p], b = v[2 * p + 1];
        unsigned ua = __float_as_uint(a), ub = __float_as_uint(b);
        hi.u[p] = (ua >> 16) | (ub & 0xFFFF0000u);
        float la = a - __uint_as_float(ua & 0xFFFF0000u);
        float lb = b - __uint_as_float(ub & 0xFFFF0000u);
        lo.u[p] = (__float_as_uint(la) >> 16) | (__float_as_uint(lb) & 0xFFFF0000u);
    }
}

// ---- kernel 1: h_e = 0.5|e|^2, h_z = 0.5|z_row|^2, init keys/loss --------
__global__ void vq_prep(const float* __restrict__ emb, const float* __restrict__ z,
                        float* __restrict__ h_e, float* __restrict__ h_z,
                        unsigned* __restrict__ k1, unsigned* __restrict__ k2,
                        float* __restrict__ out) {
    int t = blockIdx.x * 256 + threadIdx.x;   // 80*256 = 20480
    if (t < NE_) {
        const float4* er = (const float4*)(emb + (size_t)t * 64);
        float s = 0.f;
#pragma unroll
        for (int k = 0; k < 16; k++) {
            float4 e4 = er[k];
            s = fmaf(e4.x, e4.x, s); s = fmaf(e4.y, e4.y, s);
            s = fmaf(e4.z, e4.z, s); s = fmaf(e4.w, e4.w, s);
        }
        h_e[t] = 0.5f * s;
    } else {
        int n = t - NE_;                      // 0..16383
        int b = n >> 10, hw = n & 1023;
        const float* zp = z + (size_t)b * CHW_ + hw;
        float s = 0.f;
#pragma unroll
        for (int c = 0; c < 64; c++) { float v = zp[c * HW_]; s = fmaf(v, v, s); }
        h_z[n] = 0.5f * s;
        k1[n] = 0xFFFFFFFFu;
        k2[n] = 0xFFFFFFFFu;
        if (n == 0) out[LOSS_OFF] = 0.f;
    }
}

// ---- kernel 1b: precompute z bf16-split B-fragments ----------------------
// zfrag[tile(1024)][part(4: zh0,zh1,zl0,zl1)][lane(64)] x 16 B.
__global__ __launch_bounds__(256) void vq_zsplit(const float* __restrict__ z,
                                                 char* __restrict__ zfrag) {
    int u = blockIdx.x * 256 + threadIdx.x;   // 512*256 = 131072
    int l = u & 63;
    int s = (u >> 6) & 1;
    int t = u >> 7;                           // 0..1023
    int n = t * 16 + (l & 15);
    int b = n >> 10, hw = n & 1023;
    int c0 = s * 32 + (l >> 4) * 8;
    const float* zp = z + (size_t)b * CHW_ + hw;
    float v[8];
#pragma unroll
    for (int j = 0; j < 8; j++) v[j] = zp[(c0 + j) * HW_];
    FragU hi, lo;
    split8(v, hi, lo);
    char* base = zfrag + (size_t)t * 4096 + l * 16;
    *(FragU*)(base + s * 1024) = hi;
    *(FragU*)(base + (2 + s) * 1024) = lo;
}

// ---- kernel 2: MFMA scan -------------------------------------------------
// Grid 512 = 8 e-chunks x 64 row-groups. Block 256 = 4 waves, 2 blocks/CU
// (amdgpu_waves_per_eu(2,2) pins 2 waves/SIMD -> 256-VGPR budget, no spill).
// Wave owns 8 e-tiles (128 e) register-resident (negated bf16-split frags).
// h_e/h_z staged in LDS; z-frags prefetched one rt ahead.
__global__ __attribute__((amdgpu_waves_per_eu(2, 2))) __launch_bounds__(256)
void vq_mfma(const char* __restrict__ zfrag, const float* __restrict__ emb,
             const float* __restrict__ h_e, const float* __restrict__ h_z,
             unsigned* __restrict__ k1, unsigned* __restrict__ k2) {
    __shared__ float sh_he[512];
    __shared__ float sh_hz[256];

    const int tid = threadIdx.x;
    const int lane = tid & 63;
    const int wave = tid >> 6;
    const int lrow = lane & 15;       // z-row index within tile
    const int lgrp = lane >> 4;       // k-octet group / e-quartet (0..3)
    const int ecb = blockIdx.x & 7;   // e-chunk (512 e)
    const int rgb = blockIdx.x >> 3;  // row-group (256 rows)

    const int eblk = ecb * 512;
    const int ebase = eblk + wave * 128;        // wave's 128 embeddings
    const int c0 = lgrp * 8;

    sh_he[tid] = h_e[eblk + tid];
    sh_he[256 + tid] = h_e[eblk + 256 + tid];
    sh_hz[tid] = h_z[rgb * 256 + tid];

    // ---- load + split e-fragments (resident): 8 tiles x 2 k-steps --------
    FragU aeh[8][2], ael[8][2];
#pragma unroll
    for (int i = 0; i < 8; i++) {
        int eI = ebase + i * 16 + lrow;
        const float* ep = emb + (size_t)eI * 64;
#pragma unroll
        for (int s = 0; s < 2; s++) {
            float ev[8];
            const float4* e4p = (const float4*)(ep + s * 32 + c0);
            float4 ea = e4p[0], eb = e4p[1];
            ev[0] = -ea.x; ev[1] = -ea.y; ev[2] = -ea.z; ev[3] = -ea.w;
            ev[4] = -eb.x; ev[5] = -eb.y; ev[6] = -eb.z; ev[7] = -eb.w;
            split8(ev, aeh[i][s], ael[i][s]);
        }
    }
    __syncthreads();

    // ---- scan 16 row-tiles, prefetching z-frags one tile ahead ----------
    const char* zbase = zfrag + (size_t)(rgb * 16) * 4096 + lane * 16;
    bf16x8 c0v = *(const bf16x8*)(zbase);
    bf16x8 c1v = *(const bf16x8*)(zbase + 1024);
    bf16x8 c2v = *(const bf16x8*)(zbase + 2048);
    bf16x8 c3v = *(const bf16x8*)(zbase + 3072);
    float hzc = sh_hz[lrow];

    for (int rt = 0; rt < 16; rt++) {
        const int nrt = (rt < 15) ? rt + 1 : 15;           // branchless prefetch
        const char* nb = zbase + (size_t)nrt * 4096;
        bf16x8 n0 = *(const bf16x8*)(nb);
        bf16x8 n1 = *(const bf16x8*)(nb + 1024);
        bf16x8 n2 = *(const bf16x8*)(nb + 2048);
        bf16x8 n3 = *(const bf16x8*)(nb + 3072);
        float hzn = sh_hz[nrt * 16 + lrow];

        const int rowbase = rgb * 256 + rt * 16;
        unsigned s1k = 0xFFFFFFFFu, s2k = 0xFFFFFFFFu;

#pragma unroll
        for (int i = 0; i < 8; i++) {
            const float4 he = *(const float4*)&sh_he[wave * 128 + i * 16 + lgrp * 4];
            f32x4 acc;
            acc[0] = he.x + hzc; acc[1] = he.y + hzc;
            acc[2] = he.z + hzc; acc[3] = he.w + hzc;
            acc = __builtin_amdgcn_mfma_f32_16x16x32_bf16(aeh[i][0].v, c0v, acc, 0, 0, 0);
            acc = __builtin_amdgcn_mfma_f32_16x16x32_bf16(aeh[i][1].v, c1v, acc, 0, 0, 0);
            acc = __builtin_amdgcn_mfma_f32_16x16x32_bf16(ael[i][0].v, c0v, acc, 0, 0, 0);
            acc = __builtin_amdgcn_mfma_f32_16x16x32_bf16(ael[i][1].v, c1v, acc, 0, 0, 0);
            acc = __builtin_amdgcn_mfma_f32_16x16x32_bf16(aeh[i][0].v, c2v, acc, 0, 0, 0);
            acc = __builtin_amdgcn_mfma_f32_16x16x32_bf16(aeh[i][1].v, c3v, acc, 0, 0, 0);

            const unsigned eb12 = (unsigned)(ebase + i * 16 + lgrp * 4);
#pragma unroll
            for (int r = 0; r < 4; r++) {
                float sc = fmaxf(acc[r], 0.f);
                unsigned key = (__float_as_uint(sc) & 0xFFFFF000u) | (eb12 + r);
                unsigned t2 = (s1k > key) ? s1k : key;
                s2k = (s2k < t2) ? s2k : t2;
                s1k = (s1k < key) ? s1k : key;
            }
        }

        // merge across the 4 e-quartet lane-groups (same z-row)
#pragma unroll
        for (int off = 16; off <= 32; off += 16) {
            unsigned o1 = (unsigned)__shfl_xor((int)s1k, off);
            unsigned o2 = (unsigned)__shfl_xor((int)s2k, off);
            unsigned t2 = (s1k > o1) ? s1k : o1;
            unsigned m2 = (s2k < o2) ? s2k : o2;
            s2k = (m2 < t2) ? m2 : t2;
            s1k = (s1k < o1) ? s1k : o1;
        }

        if (lane < 16) {
            const int n = rowbase + lane;
            unsigned old = atomicMin(&k1[n], s1k);
            unsigned disp = (old > s1k) ? old : s1k;
            atomicMin(&k2[n], disp);
            atomicMin(&k2[n], s2k);
        }

        c0v = n0; c1v = n1; c2v = n2; c3v = n3; hzc = hzn;
    }
}

// ---- kernel 3: outputs; 4 threads/row; exact fp64 duel for near-ties -----
__global__ __launch_bounds__(256) void vq_final(
        const float* __restrict__ z, const float* __restrict__ emb,
        const unsigned* __restrict__ k1v, const unsigned* __restrict__ k2v,
        float* __restrict__ out) {
    int t = blockIdx.x * 256 + threadIdx.x;   // 256 blocks x 256 = 65536
    int n = t >> 2;                           // row
    int q = t & 3;                            // channel quarter
    unsigned key1 = k1v[n];
    unsigned key2 = k2v[n];
    int idx = (int)(key1 & 0xFFFu);
    float s1 = __uint_as_float(key1 & 0xFFFFF000u);
    float s2 = __uint_as_float(key2 & 0xFFFFF000u);

    int b = n >> 10, hw = n & 1023;
    const float* zp = z + (size_t)b * CHW_ + hw;
    const int cq = q * 16;

    if (s2 - s1 < EPS_GAP) {                   // near-tie: exact fp64 duel
        int i2 = (int)(key2 & 0xFFFu);
        const float* ea = emb + (size_t)idx * 64 + cq;
        const float* eb = emb + (size_t)i2 * 64 + cq;
        double da = 0.0, db = 0.0;
#pragma unroll
        for (int j = 0; j < 16; j++) {
            double zv = (double)zp[(cq + j) * HW_];
            double xa = (double)ea[j] - zv;
            double xb = (double)eb[j] - zv;
            da = fma(xa, xa, da);
            db = fma(xb, xb, db);
        }
#pragma unroll
        for (int off = 1; off <= 2; off <<= 1) {
            da += __shfl_xor(da, off);
            db += __shfl_xor(db, off);
        }
        if (db < da || (db == da && i2 < idx)) idx = i2;
    }

    const float* er = emb + (size_t)idx * 64 + cq;
    float* zq = out + (size_t)b * CHW_ + hw;
    float lsum = 0.f;
#pragma unroll
    for (int j = 0; j < 16; j++) {
        float e = er[j];
        float d = e - zp[(cq + j) * HW_];
        zq[(cq + j) * HW_] = e;
        lsum = fmaf(d, d, lsum);
    }
    if (q == 0) out[IDX_OFF + n] = (float)idx;

#pragma unroll
    for (int off = 32; off; off >>= 1) lsum += __shfl_down(lsum, off);
    if ((threadIdx.x & 63) == 0) atomicAdd(&out[LOSS_OFF], lsum * LOSS_SCALE);
}

extern "C" void kernel_launch(void* const* d_in, const int* in_sizes, int n_in,
                              void* d_out, int out_size, void* d_ws, size_t ws_size,
                              hipStream_t stream) {
    const float* z   = (const float*)d_in[0];
    const float* emb = (const float*)d_in[1];
    float* out = (float*)d_out;
    char* ws = (char*)d_ws;

    float* h_e   = (float*)ws;                        // 16 KB
    float* h_z   = (float*)(ws + 16384);              // 64 KB
    unsigned* k1 = (unsigned*)(ws + 81920);           // 64 KB
    unsigned* k2 = (unsigned*)(ws + 147456);          // 64 KB
    char* zfrag  = ws + 212992;                       // 4 MB

    vq_prep  <<<80, 256, 0, stream>>>(emb, z, h_e, h_z, k1, k2, out);
    vq_zsplit<<<512, 256, 0, stream>>>(z, zfrag);
    vq_mfma  <<<512, 256, 0, stream>>>(zfrag, emb, h_e, h_z, k1, k2);
    vq_final <<<256, 256, 0, stream>>>(z, emb, k1, k2, out);
}

// Round 7
// 64.391 us; speedup vs baseline: 1.0665x; 1.0459x over previous
//
#include <hip/hip_runtime.h>

typedef float f32x4 __attribute__((ext_vector_type(4)));
typedef short bf16x8 __attribute__((ext_vector_type(8)));

#define HW_ 1024
#define NE_ 4096
#define CHW_ 65536          // 64*1024
#define ZQ_SIZE 1048576
#define LOSS_OFF ZQ_SIZE
#define IDX_OFF (ZQ_SIZE + 1)
#define LOSS_SCALE (1.25f / 1048576.f)
#define EPS_GAP 0.15f       // on 0.5*d2 scale; covers 12-bit key trunc + split err

union FragU { unsigned u[4]; bf16x8 v; };

__device__ __forceinline__ unsigned umin_(unsigned a, unsigned b) { return a < b ? a : b; }
__device__ __forceinline__ unsigned umax_(unsigned a, unsigned b) { return a > b ? a : b; }

// split 8 f32 -> hi/lo bf16 fragments (truncation split; lo captures the tail)
__device__ __forceinline__ void split8(const float* v, FragU& hi, FragU& lo) {
#pragma unroll
    for (int p = 0; p < 4; p++) {
        float a = v[2 * p], b = v[2 * p + 1];
        unsigned ua = __float_as_uint(a), ub = __float_as_uint(b);
        hi.u[p] = (ua >> 16) | (ub & 0xFFFF0000u);
        float la = a - __uint_as_float(ua & 0xFFFF0000u);
        float lb = b - __uint_as_float(ub & 0xFFFF0000u);
        lo.u[p] = (__float_as_uint(la) >> 16) | (__float_as_uint(lb) & 0xFFFF0000u);
    }
}

__device__ __forceinline__ void gload_lds16(const void* g, void* l) {
    __builtin_amdgcn_global_load_lds(
        (const __attribute__((address_space(1))) unsigned*)g,
        (__attribute__((address_space(3))) unsigned*)l, 16, 0, 0);
}

// ---- kernel 1: h_e = 0.5|e|^2, h_z = 0.5|z_row|^2, zero loss -------------
__global__ void vq_prep(const float* __restrict__ emb, const float* __restrict__ z,
                        float* __restrict__ h_e, float* __restrict__ h_z,
                        float* __restrict__ out) {
    int t = blockIdx.x * 256 + threadIdx.x;   // 80*256 = 20480
    if (t < NE_) {
        const float4* er = (const float4*)(emb + (size_t)t * 64);
        float s = 0.f;
#pragma unroll
        for (int k = 0; k < 16; k++) {
            float4 e4 = er[k];
            s = fmaf(e4.x, e4.x, s); s = fmaf(e4.y, e4.y, s);
            s = fmaf(e4.z, e4.z, s); s = fmaf(e4.w, e4.w, s);
        }
        h_e[t] = 0.5f * s;
    } else {
        int n = t - NE_;                      // 0..16383
        int b = n >> 10, hw = n & 1023;
        const float* zp = z + (size_t)b * CHW_ + hw;
        float s = 0.f;
#pragma unroll
        for (int c = 0; c < 64; c++) { float v = zp[c * HW_]; s = fmaf(v, v, s); }
        h_z[n] = 0.5f * s;
        if (n == 0) out[LOSS_OFF] = 0.f;
    }
}

// ---- kernel 1b: z bf16-split B-fragments ---------------------------------
// zfrag[tile(1024)][part(4: zh0,zh1,zl0,zl1)][lane(64)] x 16 B.
__global__ __launch_bounds__(256) void vq_zsplit(const float* __restrict__ z,
                                                 char* __restrict__ zfrag) {
    int u = blockIdx.x * 256 + threadIdx.x;   // 512*256 = 131072
    int l = u & 63;
    int s = (u >> 6) & 1;
    int t = u >> 7;                           // 0..1023
    int n = t * 16 + (l & 15);
    int b = n >> 10, hw = n & 1023;
    int c0 = s * 32 + (l >> 4) * 8;
    const float* zp = z + (size_t)b * CHW_ + hw;
    float v[8];
#pragma unroll
    for (int j = 0; j < 8; j++) v[j] = zp[(c0 + j) * HW_];
    FragU hi, lo;
    split8(v, hi, lo);
    char* base = zfrag + (size_t)t * 4096 + l * 16;
    *(FragU*)(base + s * 1024) = hi;
    *(FragU*)(base + (2 + s) * 1024) = lo;
}

// ---- kernel 1c: e bf16-split A-fragments (negated) -----------------------
// efrag[tile(256)][part(4: eh0,eh1,el0,el1)][lane(64)] x 16 B.
__global__ __launch_bounds__(256) void vq_esplit(const float* __restrict__ emb,
                                                 char* __restrict__ efrag) {
    int u = blockIdx.x * 256 + threadIdx.x;   // 128*256 = 32768
    int l = u & 63;
    int s = (u >> 6) & 1;
    int t = u >> 7;                           // e-tile 0..255
    int er = t * 16 + (l & 15);
    int c0 = s * 32 + (l >> 4) * 8;
    const float* ep = emb + (size_t)er * 64 + c0;
    float4 ea = *(const float4*)(ep);
    float4 eb = *(const float4*)(ep + 4);
    float v[8];
    v[0] = -ea.x; v[1] = -ea.y; v[2] = -ea.z; v[3] = -ea.w;
    v[4] = -eb.x; v[5] = -eb.y; v[6] = -eb.z; v[7] = -eb.w;
    FragU hi, lo;
    split8(v, hi, lo);
    char* base = efrag + (size_t)t * 4096 + l * 16;
    *(FragU*)(base + s * 1024) = hi;
    *(FragU*)(base + (2 + s) * 1024) = lo;
}

// ---- kernel 2: MFMA scan, LDS-staged, no atomics -------------------------
// Grid 512 = 128 row-blocks x 4 codebook-quarters. Block 256 = 4 waves.
// Wave owns 2 row-tiles (32 rows, z-frags resident) x its quarter (1024 e).
// e-frags staged 128-e chunks into 32 KB double-buffered LDS (gload_lds).
// acc = 0.5|z|^2 + 0.5|e|^2 - e.z = 0.5*d2 >= 0; key = (bits&~0xFFF)|e_idx.
__global__ __launch_bounds__(256) void vq_mfma(
        const char* __restrict__ zfrag, const char* __restrict__ efrag,
        const float* __restrict__ h_e, const float* __restrict__ h_z,
        unsigned* __restrict__ k1q, unsigned* __restrict__ k2q) {
    __shared__ char buf[2][32768];

    const int tid = threadIdx.x;
    const int lane = tid & 63;
    const int w = tid >> 6;
    const int lrow = lane & 15;
    const int lgrp = lane >> 4;
    const int qb = blockIdx.x & 3;    // codebook quarter (1024 e)
    const int rb = blockIdx.x >> 2;   // row-block (128 rows)
    const int rt0 = rb * 8 + w * 2;   // wave's two global row-tiles
    const int rt1 = rt0 + 1;

    // stage chunk 0 (linear copy: per-lane global src, wave-uniform LDS base)
    {
        const char* src = efrag + (size_t)(qb * 64) * 4096 + w * 8192 + lane * 16;
        char* dst = (char*)buf[0] + w * 8192;
#pragma unroll
        for (int i = 0; i < 8; i++) gload_lds16(src + i * 1024, dst + i * 1024);
    }

    // z-frags resident (2 row-tiles x 4 parts)
    const char* zb0 = zfrag + (size_t)rt0 * 4096 + lane * 16;
    const char* zb1 = zfrag + (size_t)rt1 * 4096 + lane * 16;
    bf16x8 z00 = *(const bf16x8*)(zb0);
    bf16x8 z01 = *(const bf16x8*)(zb0 + 1024);
    bf16x8 z02 = *(const bf16x8*)(zb0 + 2048);
    bf16x8 z03 = *(const bf16x8*)(zb0 + 3072);
    bf16x8 z10 = *(const bf16x8*)(zb1);
    bf16x8 z11 = *(const bf16x8*)(zb1 + 1024);
    bf16x8 z12 = *(const bf16x8*)(zb1 + 2048);
    bf16x8 z13 = *(const bf16x8*)(zb1 + 3072);
    const float hz0 = h_z[rt0 * 16 + lrow];
    const float hz1 = h_z[rt1 * 16 + lrow];

    unsigned s1k0 = 0xFFFFFFFFu, s2k0 = 0xFFFFFFFFu;
    unsigned s1k1 = 0xFFFFFFFFu, s2k1 = 0xFFFFFFFFu;

    __syncthreads();                  // drains vmcnt: chunk 0 staged
    int cur = 0;
    for (int c = 0; c < 8; c++) {
        if (c < 7) {                  // issue next-chunk stage early
            const char* src = efrag + (size_t)(qb * 64 + (c + 1) * 8) * 4096
                              + w * 8192 + lane * 16;
            char* dst = (char*)buf[cur ^ 1] + w * 8192;
#pragma unroll
            for (int i = 0; i < 8; i++) gload_lds16(src + i * 1024, dst + i * 1024);
        }

        const char* cb = (const char*)buf[cur] + lane * 16;
#pragma unroll
        for (int j = 0; j < 8; j++) {
            const char* tb = cb + j * 4096;
            bf16x8 ah0 = *(const bf16x8*)(tb);
            bf16x8 ah1 = *(const bf16x8*)(tb + 1024);
            bf16x8 al0 = *(const bf16x8*)(tb + 2048);
            bf16x8 al1 = *(const bf16x8*)(tb + 3072);
            const int et = qb * 64 + c * 8 + j;
            const float4 he = *(const float4*)(h_e + et * 16 + lgrp * 4);

            f32x4 a0, a1;
            a0[0] = he.x + hz0; a0[1] = he.y + hz0;
            a0[2] = he.z + hz0; a0[3] = he.w + hz0;
            a1[0] = he.x + hz1; a1[1] = he.y + hz1;
            a1[2] = he.z + hz1; a1[3] = he.w + hz1;

            a0 = __builtin_amdgcn_mfma_f32_16x16x32_bf16(ah0, z00, a0, 0, 0, 0);
            a1 = __builtin_amdgcn_mfma_f32_16x16x32_bf16(ah0, z10, a1, 0, 0, 0);
            a0 = __builtin_amdgcn_mfma_f32_16x16x32_bf16(ah1, z01, a0, 0, 0, 0);
            a1 = __builtin_amdgcn_mfma_f32_16x16x32_bf16(ah1, z11, a1, 0, 0, 0);
            a0 = __builtin_amdgcn_mfma_f32_16x16x32_bf16(al0, z00, a0, 0, 0, 0);
            a1 = __builtin_amdgcn_mfma_f32_16x16x32_bf16(al0, z10, a1, 0, 0, 0);
            a0 = __builtin_amdgcn_mfma_f32_16x16x32_bf16(al1, z01, a0, 0, 0, 0);
            a1 = __builtin_amdgcn_mfma_f32_16x16x32_bf16(al1, z11, a1, 0, 0, 0);
            a0 = __builtin_amdgcn_mfma_f32_16x16x32_bf16(ah0, z02, a0, 0, 0, 0);
            a1 = __builtin_amdgcn_mfma_f32_16x16x32_bf16(ah0, z12, a1, 0, 0, 0);
            a0 = __builtin_amdgcn_mfma_f32_16x16x32_bf16(ah1, z03, a0, 0, 0, 0);
            a1 = __builtin_amdgcn_mfma_f32_16x16x32_bf16(ah1, z13, a1, 0, 0, 0);

            const unsigned eb12 = (unsigned)(et * 16 + lgrp * 4);
#pragma unroll
            for (int r = 0; r < 4; r++) {
                float sc0 = fmaxf(a0[r], 0.f);
                unsigned key0 = (__float_as_uint(sc0) & 0xFFFFF000u) | (eb12 + r);
                s2k0 = umin_(s2k0, umax_(s1k0, key0));
                s1k0 = umin_(s1k0, key0);
                float sc1 = fmaxf(a1[r], 0.f);
                unsigned key1 = (__float_as_uint(sc1) & 0xFFFFF000u) | (eb12 + r);
                s2k1 = umin_(s2k1, umax_(s1k1, key1));
                s1k1 = umin_(s1k1, key1);
            }
        }
        __syncthreads();              // staged c+1 landed; buf[cur] free
        cur ^= 1;
    }

    // merge across the 4 k-octet lane-groups (same z-row)
#pragma unroll
    for (int off = 16; off <= 32; off += 16) {
        unsigned o1 = (unsigned)__shfl_xor((int)s1k0, off);
        unsigned o2 = (unsigned)__shfl_xor((int)s2k0, off);
        s2k0 = umin_(umin_(s2k0, o2), umax_(s1k0, o1));
        s1k0 = umin_(s1k0, o1);
        unsigned p1 = (unsigned)__shfl_xor((int)s1k1, off);
        unsigned p2 = (unsigned)__shfl_xor((int)s2k1, off);
        s2k1 = umin_(umin_(s2k1, p2), umax_(s1k1, p1));
        s1k1 = umin_(s1k1, p1);
    }

    if (lane < 16) {                  // plain stores; one owner per (row, quarter)
        const int base = qb * 16384;
        k1q[base + rt0 * 16 + lane] = s1k0;
        k2q[base + rt0 * 16 + lane] = s2k0;
        k1q[base + rt1 * 16 + lane] = s1k1;
        k2q[base + rt1 * 16 + lane] = s2k1;
    }
}

// ---- kernel 3: merge 4 quarters; outputs; fp64 duel for near-ties --------
__global__ __launch_bounds__(256) void vq_final(
        const float* __restrict__ z, const float* __restrict__ emb,
        const unsigned* __restrict__ k1q, const unsigned* __restrict__ k2q,
        float* __restrict__ out) {
    int t = blockIdx.x * 256 + threadIdx.x;   // 256 blocks x 256 = 65536
    int n = t >> 2;                           // row
    int q = t & 3;                            // channel quarter
    unsigned a0 = k1q[n],         a1 = k1q[16384 + n];
    unsigned a2 = k1q[32768 + n], a3 = k1q[49152 + n];
    unsigned b0 = k2q[n],         b1 = k2q[16384 + n];
    unsigned b2 = k2q[32768 + n], b3 = k2q[49152 + n];
    unsigned m01 = umin_(a0, a1), x01 = umax_(a0, a1);
    unsigned m23 = umin_(a2, a3), x23 = umax_(a2, a3);
    unsigned key1 = umin_(m01, m23);
    unsigned sec  = umin_(umax_(m01, m23), umin_(x01, x23));
    unsigned key2 = umin_(sec, umin_(umin_(b0, b1), umin_(b2, b3)));

    int idx = (int)(key1 & 0xFFFu);
    float s1 = __uint_as_float(key1 & 0xFFFFF000u);
    float s2 = __uint_as_float(key2 & 0xFFFFF000u);

    int b = n >> 10, hw = n & 1023;
    const float* zp = z + (size_t)b * CHW_ + hw;
    const int cq = q * 16;

    if (s2 - s1 < EPS_GAP) {                   // near-tie: exact fp64 duel
        int i2 = (int)(key2 & 0xFFFu);
        const float* ea = emb + (size_t)idx * 64 + cq;
        const float* eb = emb + (size_t)i2 * 64 + cq;
        double da = 0.0, db = 0.0;
#pragma unroll
        for (int j = 0; j < 16; j++) {
            double zv = (double)zp[(cq + j) * HW_];
            double xa = (double)ea[j] - zv;
            double xb = (double)eb[j] - zv;
            da = fma(xa, xa, da);
            db = fma(xb, xb, db);
        }
#pragma unroll
        for (int off = 1; off <= 2; off <<= 1) {
            da += __shfl_xor(da, off);
            db += __shfl_xor(db, off);
        }
        if (db < da || (db == da && i2 < idx)) idx = i2;
    }

    const float* er = emb + (size_t)idx * 64 + cq;
    float* zq = out + (size_t)b * CHW_ + hw;
    float lsum = 0.f;
#pragma unroll
    for (int j = 0; j < 16; j++) {
        float e = er[j];
        float d = e - zp[(cq + j) * HW_];
        zq[(cq + j) * HW_] = e;
        lsum = fmaf(d, d, lsum);
    }
    if (q == 0) out[IDX_OFF + n] = (float)idx;

#pragma unroll
    for (int off = 32; off; off >>= 1) lsum += __shfl_down(lsum, off);
    if ((threadIdx.x & 63) == 0) atomicAdd(&out[LOSS_OFF], lsum * LOSS_SCALE);
}

extern "C" void kernel_launch(void* const* d_in, const int* in_sizes, int n_in,
                              void* d_out, int out_size, void* d_ws, size_t ws_size,
                              hipStream_t stream) {
    const float* z   = (const float*)d_in[0];
    const float* emb = (const float*)d_in[1];
    float* out = (float*)d_out;
    char* ws = (char*)d_ws;

    float* h_e   = (float*)ws;                        // 16 KB
    float* h_z   = (float*)(ws + 16384);              // 64 KB
    unsigned* k1q = (unsigned*)(ws + 81920);          // 256 KB (4 quarters)
    unsigned* k2q = (unsigned*)(ws + 344064);         // 256 KB
    char* zfrag  = ws + 606208;                       // 4 MB
    char* efrag  = ws + 4800512;                      // 1 MB

    vq_prep  <<<80, 256, 0, stream>>>(emb, z, h_e, h_z, out);
    vq_zsplit<<<512, 256, 0, stream>>>(z, zfrag);
    vq_esplit<<<128, 256, 0, stream>>>(emb, efrag);
    vq_mfma  <<<512, 256, 0, stream>>>(zfrag, efrag, h_e, h_z, k1q, k2q);
    vq_final <<<256, 256, 0, stream>>>(z, emb, k1q, k2q, out);
}

// Round 9
// 63.882 us; speedup vs baseline: 1.0750x; 1.0080x over previous
//
#include <hip/hip_runtime.h>

typedef float f32x4 __attribute__((ext_vector_type(4)));
typedef short bf16x8 __attribute__((ext_vector_type(8)));

#define HW_ 1024
#define NE_ 4096
#define CHW_ 65536          // 64*1024
#define ZQ_SIZE 1048576
#define LOSS_OFF ZQ_SIZE
#define IDX_OFF (ZQ_SIZE + 1)
#define LOSS_SCALE (1.25f / 1048576.f)
#define EPS_GAP 0.1f        // 0.5*d2 scale; covers 12-bit trunc (<=0.03) + split err (~1e-5)

union FragU { unsigned u[4]; bf16x8 v; };

__device__ __forceinline__ unsigned umin_(unsigned a, unsigned b) { return a < b ? a : b; }
__device__ __forceinline__ unsigned umax_(unsigned a, unsigned b) { return a > b ? a : b; }

// split 8 f32 -> hi/lo bf16 fragments (truncation split; lo captures the tail)
__device__ __forceinline__ void split8(const float* v, FragU& hi, FragU& lo) {
#pragma unroll
    for (int p = 0; p < 4; p++) {
        float a = v[2 * p], b = v[2 * p + 1];
        unsigned ua = __float_as_uint(a), ub = __float_as_uint(b);
        hi.u[p] = (ua >> 16) | (ub & 0xFFFF0000u);
        float la = a - __uint_as_float(ua & 0xFFFF0000u);
        float lb = b - __uint_as_float(ub & 0xFFFF0000u);
        lo.u[p] = (__float_as_uint(la) >> 16) | (__float_as_uint(lb) & 0xFFFF0000u);
    }
}

__device__ __forceinline__ void gload_lds16(const void* g, void* l) {
    __builtin_amdgcn_global_load_lds(
        (const __attribute__((address_space(1))) unsigned*)g,
        (__attribute__((address_space(3))) unsigned*)l, 16, 0, 0);
}

// ---- kernel 1 (fused pre): z split (4 parts) | e split | norms -----------
// blocks [0,512): zfrag hi+lo; [512,640): efrag (negated); [640,720): norms.
__global__ __launch_bounds__(256) void vq_pre(
        const float* __restrict__ z, const float* __restrict__ emb,
        float* __restrict__ h_e, float* __restrict__ h_z,
        char* __restrict__ zfrag, char* __restrict__ efrag,
        float* __restrict__ out) {
    const int bid = blockIdx.x, tid = threadIdx.x;
    if (bid < 512) {                       // z fragments: [tile][zh0,zh1,zl0,zl1][lane]
        int u = bid * 256 + tid;
        int l = u & 63, s = (u >> 6) & 1, t = u >> 7;   // t 0..1023
        int n = t * 16 + (l & 15);
        int b = n >> 10, hw = n & 1023;
        int c0 = s * 32 + (l >> 4) * 8;
        const float* zp = z + (size_t)b * CHW_ + hw;
        float v[8];
#pragma unroll
        for (int j = 0; j < 8; j++) v[j] = zp[(c0 + j) * HW_];
        FragU hi, lo;
        split8(v, hi, lo);
        char* base = zfrag + (size_t)t * 4096 + l * 16;
        *(FragU*)(base + s * 1024) = hi;
        *(FragU*)(base + (2 + s) * 1024) = lo;
    } else if (bid < 640) {                // e fragments, negated (4 KB/tile)
        int u = (bid - 512) * 256 + tid;
        int l = u & 63, s = (u >> 6) & 1, t = u >> 7;   // t 0..255
        int er = t * 16 + (l & 15);
        int c0 = s * 32 + (l >> 4) * 8;
        const float* ep = emb + (size_t)er * 64 + c0;
        float4 ea = *(const float4*)(ep);
        float4 eb = *(const float4*)(ep + 4);
        float v[8];
        v[0] = -ea.x; v[1] = -ea.y; v[2] = -ea.z; v[3] = -ea.w;
        v[4] = -eb.x; v[5] = -eb.y; v[6] = -eb.z; v[7] = -eb.w;
        FragU hi, lo;
        split8(v, hi, lo);
        char* base = efrag + (size_t)t * 4096 + l * 16;
        *(FragU*)(base + s * 1024) = hi;
        *(FragU*)(base + (2 + s) * 1024) = lo;
    } else {                               // norms
        int t = (bid - 640) * 256 + tid;   // 0..20479
        if (t < NE_) {
            const float4* er = (const float4*)(emb + (size_t)t * 64);
            float s = 0.f;
#pragma unroll
            for (int k = 0; k < 16; k++) {
                float4 e4 = er[k];
                s = fmaf(e4.x, e4.x, s); s = fmaf(e4.y, e4.y, s);
                s = fmaf(e4.z, e4.z, s); s = fmaf(e4.w, e4.w, s);
            }
            h_e[t] = 0.5f * s;
        } else {
            int n = t - NE_;
            int b = n >> 10, hw = n & 1023;
            const float* zp = z + (size_t)b * CHW_ + hw;
            float s = 0.f;
#pragma unroll
            for (int c = 0; c < 64; c++) { float v = zp[c * HW_]; s = fmaf(v, v, s); }
            h_z[n] = 0.5f * s;
            if (n == 0) out[LOSS_OFF] = 0.f;
        }
    }
}

// ---- kernel 2: MFMA scan. 3-term split, 4 row-tiles/wave -----------------
// Grid 512 = 64 row-blocks x 8 e-chunks (512 e) -> 2 blocks/CU. 4 waves.
// Wave: 4 row-tiles (zh+zl resident) x 512 e. e staged 4-tile (16 KB)
// chunks into double-buffered LDS. Per e-tile j: 5 ds_read -> 24 MFMA.
// acc = 0.5|z|^2 + 0.5|e|^2 - e.z_h - e_l.z_h ... = 0.5*d2 + el.zl (~1e-5).
// key = (f32 bits & ~0xFFF) | e_idx ; u32 min == lexicographic argmin.
__global__ void vq_mfma(
        const char* __restrict__ zfrag, const char* __restrict__ efrag,
        const float* __restrict__ h_e, const float* __restrict__ h_z,
        unsigned* __restrict__ k1q, unsigned* __restrict__ k2q) {
    __shared__ char buf[2][16384];
    __shared__ __attribute__((aligned(16))) float sh_he[512];

    const int tid = threadIdx.x;
    const int lane = tid & 63;
    const int w = tid >> 6;
    const int lrow = lane & 15;
    const int lgrp = lane >> 4;
    const int ec = blockIdx.x & 7;    // e-chunk (512 e)
    const int rb = blockIdx.x >> 3;   // row-block (256 rows)
    const int rt0 = rb * 16 + w * 4;  // wave's four row-tiles

    sh_he[tid] = h_e[ec * 512 + tid];
    sh_he[256 + tid] = h_e[ec * 512 + 256 + tid];

    // stage chunk 0 (wave w copies e-tile w of the chunk; linear both sides)
    {
        const char* src = efrag + (size_t)(ec * 32 + w) * 4096 + lane * 16;
        char* dst = buf[0] + w * 4096;
#pragma unroll
        for (int i = 0; i < 4; i++) gload_lds16(src + i * 1024, dst + i * 1024);
    }

    // z frags resident: 4 row-tiles x (hi,lo) x 2 k-halves
    bf16x8 zh[4][2], zl[4][2];
    float hz[4];
#pragma unroll
    for (int r = 0; r < 4; r++) {
        const char* zb = zfrag + (size_t)(rt0 + r) * 4096 + lane * 16;
        zh[r][0] = *(const bf16x8*)(zb);
        zh[r][1] = *(const bf16x8*)(zb + 1024);
        zl[r][0] = *(const bf16x8*)(zb + 2048);
        zl[r][1] = *(const bf16x8*)(zb + 3072);
        hz[r] = h_z[(rt0 + r) * 16 + lrow];
    }

    unsigned s1k[4] = {~0u, ~0u, ~0u, ~0u};
    unsigned s2k[4] = {~0u, ~0u, ~0u, ~0u};

    __syncthreads();                  // chunk 0 staged (barrier drains vmcnt)
    int cur = 0;
    for (int c = 0; c < 8; c++) {
        if (c < 7) {                  // issue next-chunk stage early
            const char* src = efrag + (size_t)(ec * 32 + (c + 1) * 4 + w) * 4096
                              + lane * 16;
            char* dst = buf[cur ^ 1] + w * 4096;
#pragma unroll
            for (int i = 0; i < 4; i++) gload_lds16(src + i * 1024, dst + i * 1024);
        }

        const char* cb = buf[cur] + lane * 16;
#pragma unroll
        for (int j = 0; j < 4; j++) {
            const char* tb = cb + j * 4096;
            bf16x8 ah0 = *(const bf16x8*)(tb);
            bf16x8 ah1 = *(const bf16x8*)(tb + 1024);
            bf16x8 al0 = *(const bf16x8*)(tb + 2048);
            bf16x8 al1 = *(const bf16x8*)(tb + 3072);
            const int et4 = (c * 4 + j) * 16 + lgrp * 4;   // local e base
            const f32x4 he = *(const f32x4*)&sh_he[et4];

            f32x4 a0 = he + hz[0], a1 = he + hz[1];
            f32x4 a2 = he + hz[2], a3 = he + hz[3];

            // term 1: eh . zh
            a0 = __builtin_amdgcn_mfma_f32_16x16x32_bf16(ah0, zh[0][0], a0, 0, 0, 0);
            a1 = __builtin_amdgcn_mfma_f32_16x16x32_bf16(ah0, zh[1][0], a1, 0, 0, 0);
            a2 = __builtin_amdgcn_mfma_f32_16x16x32_bf16(ah0, zh[2][0], a2, 0, 0, 0);
            a3 = __builtin_amdgcn_mfma_f32_16x16x32_bf16(ah0, zh[3][0], a3, 0, 0, 0);
            a0 = __builtin_amdgcn_mfma_f32_16x16x32_bf16(ah1, zh[0][1], a0, 0, 0, 0);
            a1 = __builtin_amdgcn_mfma_f32_16x16x32_bf16(ah1, zh[1][1], a1, 0, 0, 0);
            a2 = __builtin_amdgcn_mfma_f32_16x16x32_bf16(ah1, zh[2][1], a2, 0, 0, 0);
            a3 = __builtin_amdgcn_mfma_f32_16x16x32_bf16(ah1, zh[3][1], a3, 0, 0, 0);
            // term 2: el . zh
            a0 = __builtin_amdgcn_mfma_f32_16x16x32_bf16(al0, zh[0][0], a0, 0, 0, 0);
            a1 = __builtin_amdgcn_mfma_f32_16x16x32_bf16(al0, zh[1][0], a1, 0, 0, 0);
            a2 = __builtin_amdgcn_mfma_f32_16x16x32_bf16(al0, zh[2][0], a2, 0, 0, 0);
            a3 = __builtin_amdgcn_mfma_f32_16x16x32_bf16(al0, zh[3][0], a3, 0, 0, 0);
            a0 = __builtin_amdgcn_mfma_f32_16x16x32_bf16(al1, zh[0][1], a0, 0, 0, 0);
            a1 = __builtin_amdgcn_mfma_f32_16x16x32_bf16(al1, zh[1][1], a1, 0, 0, 0);
            a2 = __builtin_amdgcn_mfma_f32_16x16x32_bf16(al1, zh[2][1], a2, 0, 0, 0);
            a3 = __builtin_amdgcn_mfma_f32_16x16x32_bf16(al1, zh[3][1], a3, 0, 0, 0);
            // term 3: eh . zl
            a0 = __builtin_amdgcn_mfma_f32_16x16x32_bf16(ah0, zl[0][0], a0, 0, 0, 0);
            a1 = __builtin_amdgcn_mfma_f32_16x16x32_bf16(ah0, zl[1][0], a1, 0, 0, 0);
            a2 = __builtin_amdgcn_mfma_f32_16x16x32_bf16(ah0, zl[2][0], a2, 0, 0, 0);
            a3 = __builtin_amdgcn_mfma_f32_16x16x32_bf16(ah0, zl[3][0], a3, 0, 0, 0);
            a0 = __builtin_amdgcn_mfma_f32_16x16x32_bf16(ah1, zl[0][1], a0, 0, 0, 0);
            a1 = __builtin_amdgcn_mfma_f32_16x16x32_bf16(ah1, zl[1][1], a1, 0, 0, 0);
            a2 = __builtin_amdgcn_mfma_f32_16x16x32_bf16(ah1, zl[2][1], a2, 0, 0, 0);
            a3 = __builtin_amdgcn_mfma_f32_16x16x32_bf16(ah1, zl[3][1], a3, 0, 0, 0);

            const unsigned eb12 = (unsigned)(ec * 512 + et4);
#pragma unroll
            for (int rr = 0; rr < 4; rr++) {
                unsigned key0 = (__float_as_uint(a0[rr]) & 0xFFFFF000u) | (eb12 + rr);
                s2k[0] = umin_(s2k[0], umax_(s1k[0], key0));
                s1k[0] = umin_(s1k[0], key0);
                unsigned key1 = (__float_as_uint(a1[rr]) & 0xFFFFF000u) | (eb12 + rr);
                s2k[1] = umin_(s2k[1], umax_(s1k[1], key1));
                s1k[1] = umin_(s1k[1], key1);
                unsigned key2 = (__float_as_uint(a2[rr]) & 0xFFFFF000u) | (eb12 + rr);
                s2k[2] = umin_(s2k[2], umax_(s1k[2], key2));
                s1k[2] = umin_(s1k[2], key2);
                unsigned key3 = (__float_as_uint(a3[rr]) & 0xFFFFF000u) | (eb12 + rr);
                s2k[3] = umin_(s2k[3], umax_(s1k[3], key3));
                s1k[3] = umin_(s1k[3], key3);
            }
        }
        __syncthreads();              // next chunk landed; buf[cur] free
        cur ^= 1;
    }

    // merge across the 4 k-octet lane-groups (same z-row)
#pragma unroll
    for (int off = 16; off <= 32; off += 16) {
#pragma unroll
        for (int r = 0; r < 4; r++) {
            unsigned o1 = (unsigned)__shfl_xor((int)s1k[r], off);
            unsigned o2 = (unsigned)__shfl_xor((int)s2k[r], off);
            s2k[r] = umin_(umin_(s2k[r], o2), umax_(s1k[r], o1));
            s1k[r] = umin_(s1k[r], o1);
        }
    }

    if (lane < 16) {                  // plain stores; one owner per (row, ec)
        const int base = ec * 16384;
#pragma unroll
        for (int r = 0; r < 4; r++) {
            k1q[base + (rt0 + r) * 16 + lane] = s1k[r];
            k2q[base + (rt0 + r) * 16 + lane] = s2k[r];
        }
    }
}

// ---- kernel 3: merge 8 partials; outputs; fp64 duel for near-ties --------
// Plane-major: thread t -> row n = t & 16383, channel quarter q = t >> 14.
__global__ __launch_bounds__(256) void vq_final(
        const float* __restrict__ z, const float* __restrict__ emb,
        const unsigned* __restrict__ k1q, const unsigned* __restrict__ k2q,
        float* __restrict__ out) {
    int t = blockIdx.x * 256 + threadIdx.x;   // 256 blocks x 256 = 65536
    int n = t & 16383;
    int q = t >> 14;

    unsigned m = 0xFFFFFFFFu, s = 0xFFFFFFFFu;
#pragma unroll
    for (int i = 0; i < 8; i++) {
        unsigned a = k1q[i * 16384 + n];
        unsigned b = k2q[i * 16384 + n];
        unsigned hi = umax_(m, a);
        m = umin_(m, a);
        s = umin_(umin_(s, b), hi);
    }

    int idx = (int)(m & 0xFFFu);
    float s1 = __uint_as_float(m & 0xFFFFF000u);
    float s2 = __uint_as_float(s & 0xFFFFF000u);

    int b = n >> 10, hw = n & 1023;
    const float* zp = z + (size_t)b * CHW_ + hw;
    const int cq = q * 16;

    if (s2 - s1 < EPS_GAP) {                   // near-tie: exact fp64 duel
        int i2 = (int)(s & 0xFFFu);
        const float* ea = emb + (size_t)idx * 64;
        const float* eb = emb + (size_t)i2 * 64;
        double da = 0.0, db = 0.0;
#pragma unroll 8
        for (int c = 0; c < 64; c++) {
            double zv = (double)zp[c * HW_];
            double xa = (double)ea[c] - zv;
            double xb = (double)eb[c] - zv;
            da = fma(xa, xa, da);
            db = fma(xb, xb, db);
        }
        if (db < da || (db == da && i2 < idx)) idx = i2;
    }

    const float* er = emb + (size_t)idx * 64 + cq;
    float* zq = out + (size_t)b * CHW_ + hw;
    float lsum = 0.f;
#pragma unroll
    for (int j = 0; j < 16; j++) {
        float e = er[j];
        float d = e - zp[(cq + j) * HW_];
        zq[(cq + j) * HW_] = e;
        lsum = fmaf(d, d, lsum);
    }
    if (q == 0) out[IDX_OFF + n] = (float)idx;

#pragma unroll
    for (int off = 32; off; off >>= 1) lsum += __shfl_down(lsum, off);
    if ((threadIdx.x & 63) == 0) atomicAdd(&out[LOSS_OFF], lsum * LOSS_SCALE);
}

extern "C" void kernel_launch(void* const* d_in, const int* in_sizes, int n_in,
                              void* d_out, int out_size, void* d_ws, size_t ws_size,
                              hipStream_t stream) {
    const float* z   = (const float*)d_in[0];
    const float* emb = (const float*)d_in[1];
    float* out = (float*)d_out;
    char* ws = (char*)d_ws;

    float* h_e    = (float*)ws;                       // 16 KB
    float* h_z    = (float*)(ws + 16384);             // 64 KB
    unsigned* k1q = (unsigned*)(ws + 81920);          // 512 KB (8 partials)
    unsigned* k2q = (unsigned*)(ws + 606208);         // 512 KB
    char* zfrag   = ws + 1130496;                     // 4 MB
    char* efrag   = ws + 5324800;                     // 1 MB

    vq_pre  <<<720, 256, 0, stream>>>(z, emb, h_e, h_z, zfrag, efrag, out);
    vq_mfma <<<512, 256, 0, stream>>>(zfrag, efrag, h_e, h_z, k1q, k2q);
    vq_final<<<256, 256, 0, stream>>>(z, emb, k1q, k2q, out);
}

// Round 10
// 62.053 us; speedup vs baseline: 1.1067x; 1.0295x over previous
//
#include <hip/hip_runtime.h>

typedef float f32x4 __attribute__((ext_vector_type(4)));
typedef short bf16x8 __attribute__((ext_vector_type(8)));

#define HW_ 1024
#define NE_ 4096
#define CHW_ 65536          // 64*1024
#define ZQ_SIZE 1048576
#define LOSS_OFF ZQ_SIZE
#define IDX_OFF (ZQ_SIZE + 1)
#define LOSS_SCALE (1.25f / 1048576.f)
#define EPS_GAP 0.1f        // 0.5*d2 scale; covers 12-bit trunc (<=0.03) + split err (~1e-5)

union FragU { unsigned u[4]; bf16x8 v; };

__device__ __forceinline__ unsigned umin_(unsigned a, unsigned b) { return a < b ? a : b; }
__device__ __forceinline__ unsigned umax_(unsigned a, unsigned b) { return a > b ? a : b; }

// split 8 f32 -> hi/lo bf16 fragments (truncation split; lo captures the tail)
__device__ __forceinline__ void split8(const float* v, FragU& hi, FragU& lo) {
#pragma unroll
    for (int p = 0; p < 4; p++) {
        float a = v[2 * p], b = v[2 * p + 1];
        unsigned ua = __float_as_uint(a), ub = __float_as_uint(b);
        hi.u[p] = (ua >> 16) | (ub & 0xFFFF0000u);
        float la = a - __uint_as_float(ua & 0xFFFF0000u);
        float lb = b - __uint_as_float(ub & 0xFFFF0000u);
        lo.u[p] = (__float_as_uint(la) >> 16) | (__float_as_uint(lb) & 0xFFFF0000u);
    }
}

// ---- kernel 1 (fused pre): z split (4 parts) | e split | norms -----------
// blocks [0,512): zfrag hi+lo; [512,640): efrag (negated); [640,720): norms.
__global__ __launch_bounds__(256) void vq_pre(
        const float* __restrict__ z, const float* __restrict__ emb,
        float* __restrict__ h_e, float* __restrict__ h_z,
        char* __restrict__ zfrag, char* __restrict__ efrag,
        float* __restrict__ out) {
    const int bid = blockIdx.x, tid = threadIdx.x;
    if (bid < 512) {                       // z fragments: [tile][zh0,zh1,zl0,zl1][lane]
        int u = bid * 256 + tid;
        int l = u & 63, s = (u >> 6) & 1, t = u >> 7;   // t 0..1023
        int n = t * 16 + (l & 15);
        int b = n >> 10, hw = n & 1023;
        int c0 = s * 32 + (l >> 4) * 8;
        const float* zp = z + (size_t)b * CHW_ + hw;
        float v[8];
#pragma unroll
        for (int j = 0; j < 8; j++) v[j] = zp[(c0 + j) * HW_];
        FragU hi, lo;
        split8(v, hi, lo);
        char* base = zfrag + (size_t)t * 4096 + l * 16;
        *(FragU*)(base + s * 1024) = hi;
        *(FragU*)(base + (2 + s) * 1024) = lo;
    } else if (bid < 640) {                // e fragments, negated (4 KB/tile)
        int u = (bid - 512) * 256 + tid;
        int l = u & 63, s = (u >> 6) & 1, t = u >> 7;   // t 0..255
        int er = t * 16 + (l & 15);
        int c0 = s * 32 + (l >> 4) * 8;
        const float* ep = emb + (size_t)er * 64 + c0;
        float4 ea = *(const float4*)(ep);
        float4 eb = *(const float4*)(ep + 4);
        float v[8];
        v[0] = -ea.x; v[1] = -ea.y; v[2] = -ea.z; v[3] = -ea.w;
        v[4] = -eb.x; v[5] = -eb.y; v[6] = -eb.z; v[7] = -eb.w;
        FragU hi, lo;
        split8(v, hi, lo);
        char* base = efrag + (size_t)t * 4096 + l * 16;
        *(FragU*)(base + s * 1024) = hi;
        *(FragU*)(base + (2 + s) * 1024) = lo;
    } else {                               // norms
        int t = (bid - 640) * 256 + tid;   // 0..20479
        if (t < NE_) {
            const float4* er = (const float4*)(emb + (size_t)t * 64);
            float s = 0.f;
#pragma unroll
            for (int k = 0; k < 16; k++) {
                float4 e4 = er[k];
                s = fmaf(e4.x, e4.x, s); s = fmaf(e4.y, e4.y, s);
                s = fmaf(e4.z, e4.z, s); s = fmaf(e4.w, e4.w, s);
            }
            h_e[t] = 0.5f * s;
        } else {
            int n = t - NE_;
            int b = n >> 10, hw = n & 1023;
            const float* zp = z + (size_t)b * CHW_ + hw;
            float s = 0.f;
#pragma unroll
            for (int c = 0; c < 64; c++) { float v = zp[c * HW_]; s = fmaf(v, v, s); }
            h_z[n] = 0.5f * s;
            if (n == 0) out[LOSS_OFF] = 0.f;
        }
    }
}

// ---- kernel 2: MFMA scan. NO LDS, NO barriers. ---------------------------
// 4096 waves = 256 row-waves (4 row-tiles resident) x 16 e-subranges (256 e).
// Block b: rw = b>>2, wave w covers esub = (b&3)*4 + w  (XCD stride-8 blocks
// share esubs -> per-XCD L2 reuse of efrag; 4 waves share zfrag via L1).
// Per e-tile: 4 global b128 (e-frags) + 24 MFMA + 16 keys. Latency hidden by
// TLP only. acc = 0.5|z|^2+0.5|e|^2 - eh.zh - el.zh - eh.zl = 0.5*d2 + ~1e-5.
// key = (f32 bits & ~0xFFF) | e_idx ; u32 min == lexicographic argmin.
__global__ __launch_bounds__(256) void vq_mfma(
        const char* __restrict__ zfrag, const char* __restrict__ efrag,
        const float* __restrict__ h_e, const float* __restrict__ h_z,
        unsigned* __restrict__ k1q, unsigned* __restrict__ k2q) {
    const int tid = threadIdx.x;
    const int lane = tid & 63;
    const int w = tid >> 6;
    const int lrow = lane & 15;
    const int lgrp = lane >> 4;
    const int rw = blockIdx.x >> 2;   // row-wave group: 4 row-tiles
    const int es = (blockIdx.x & 3) * 4 + w;   // e-subrange (256 e)
    const int rt0 = rw * 4;

    // z frags resident: 4 row-tiles x (hi,lo) x 2 k-halves = 64 VGPR
    bf16x8 zh[4][2], zl[4][2];
    float hz[4];
#pragma unroll
    for (int r = 0; r < 4; r++) {
        const char* zb = zfrag + (size_t)(rt0 + r) * 4096 + lane * 16;
        zh[r][0] = *(const bf16x8*)(zb);
        zh[r][1] = *(const bf16x8*)(zb + 1024);
        zl[r][0] = *(const bf16x8*)(zb + 2048);
        zl[r][1] = *(const bf16x8*)(zb + 3072);
        hz[r] = h_z[(rt0 + r) * 16 + lrow];
    }

    unsigned s1k[4] = {~0u, ~0u, ~0u, ~0u};
    unsigned s2k[4] = {~0u, ~0u, ~0u, ~0u};

    const char* ebase = efrag + (size_t)(es * 16) * 4096 + lane * 16;
    const float* hebase = h_e + es * 256 + lgrp * 4;

    for (int i = 0; i < 16; i++) {
        const char* tb = ebase + (size_t)i * 4096;
        bf16x8 ah0 = *(const bf16x8*)(tb);
        bf16x8 ah1 = *(const bf16x8*)(tb + 1024);
        bf16x8 al0 = *(const bf16x8*)(tb + 2048);
        bf16x8 al1 = *(const bf16x8*)(tb + 3072);
        const f32x4 he = *(const f32x4*)(hebase + i * 16);

        f32x4 a0 = he + hz[0], a1 = he + hz[1];
        f32x4 a2 = he + hz[2], a3 = he + hz[3];

        // term 1: eh . zh
        a0 = __builtin_amdgcn_mfma_f32_16x16x32_bf16(ah0, zh[0][0], a0, 0, 0, 0);
        a1 = __builtin_amdgcn_mfma_f32_16x16x32_bf16(ah0, zh[1][0], a1, 0, 0, 0);
        a2 = __builtin_amdgcn_mfma_f32_16x16x32_bf16(ah0, zh[2][0], a2, 0, 0, 0);
        a3 = __builtin_amdgcn_mfma_f32_16x16x32_bf16(ah0, zh[3][0], a3, 0, 0, 0);
        a0 = __builtin_amdgcn_mfma_f32_16x16x32_bf16(ah1, zh[0][1], a0, 0, 0, 0);
        a1 = __builtin_amdgcn_mfma_f32_16x16x32_bf16(ah1, zh[1][1], a1, 0, 0, 0);
        a2 = __builtin_amdgcn_mfma_f32_16x16x32_bf16(ah1, zh[2][1], a2, 0, 0, 0);
        a3 = __builtin_amdgcn_mfma_f32_16x16x32_bf16(ah1, zh[3][1], a3, 0, 0, 0);
        // term 2: el . zh
        a0 = __builtin_amdgcn_mfma_f32_16x16x32_bf16(al0, zh[0][0], a0, 0, 0, 0);
        a1 = __builtin_amdgcn_mfma_f32_16x16x32_bf16(al0, zh[1][0], a1, 0, 0, 0);
        a2 = __builtin_amdgcn_mfma_f32_16x16x32_bf16(al0, zh[2][0], a2, 0, 0, 0);
        a3 = __builtin_amdgcn_mfma_f32_16x16x32_bf16(al0, zh[3][0], a3, 0, 0, 0);
        a0 = __builtin_amdgcn_mfma_f32_16x16x32_bf16(al1, zh[0][1], a0, 0, 0, 0);
        a1 = __builtin_amdgcn_mfma_f32_16x16x32_bf16(al1, zh[1][1], a1, 0, 0, 0);
        a2 = __builtin_amdgcn_mfma_f32_16x16x32_bf16(al1, zh[2][1], a2, 0, 0, 0);
        a3 = __builtin_amdgcn_mfma_f32_16x16x32_bf16(al1, zh[3][1], a3, 0, 0, 0);
        // term 3: eh . zl
        a0 = __builtin_amdgcn_mfma_f32_16x16x32_bf16(ah0, zl[0][0], a0, 0, 0, 0);
        a1 = __builtin_amdgcn_mfma_f32_16x16x32_bf16(ah0, zl[1][0], a1, 0, 0, 0);
        a2 = __builtin_amdgcn_mfma_f32_16x16x32_bf16(ah0, zl[2][0], a2, 0, 0, 0);
        a3 = __builtin_amdgcn_mfma_f32_16x16x32_bf16(ah0, zl[3][0], a3, 0, 0, 0);
        a0 = __builtin_amdgcn_mfma_f32_16x16x32_bf16(ah1, zl[0][1], a0, 0, 0, 0);
        a1 = __builtin_amdgcn_mfma_f32_16x16x32_bf16(ah1, zl[1][1], a1, 0, 0, 0);
        a2 = __builtin_amdgcn_mfma_f32_16x16x32_bf16(ah1, zl[2][1], a2, 0, 0, 0);
        a3 = __builtin_amdgcn_mfma_f32_16x16x32_bf16(ah1, zl[3][1], a3, 0, 0, 0);

        const unsigned eb12 = (unsigned)(es * 256 + i * 16 + lgrp * 4);
#pragma unroll
        for (int rr = 0; rr < 4; rr++) {
            unsigned key0 = (__float_as_uint(a0[rr]) & 0xFFFFF000u) | (eb12 + rr);
            s2k[0] = umin_(s2k[0], umax_(s1k[0], key0));
            s1k[0] = umin_(s1k[0], key0);
            unsigned key1 = (__float_as_uint(a1[rr]) & 0xFFFFF000u) | (eb12 + rr);
            s2k[1] = umin_(s2k[1], umax_(s1k[1], key1));
            s1k[1] = umin_(s1k[1], key1);
            unsigned key2 = (__float_as_uint(a2[rr]) & 0xFFFFF000u) | (eb12 + rr);
            s2k[2] = umin_(s2k[2], umax_(s1k[2], key2));
            s1k[2] = umin_(s1k[2], key2);
            unsigned key3 = (__float_as_uint(a3[rr]) & 0xFFFFF000u) | (eb12 + rr);
            s2k[3] = umin_(s2k[3], umax_(s1k[3], key3));
            s1k[3] = umin_(s1k[3], key3);
        }
    }

    // merge across the 4 k-octet lane-groups (same z-row)
#pragma unroll
    for (int off = 16; off <= 32; off += 16) {
#pragma unroll
        for (int r = 0; r < 4; r++) {
            unsigned o1 = (unsigned)__shfl_xor((int)s1k[r], off);
            unsigned o2 = (unsigned)__shfl_xor((int)s2k[r], off);
            s2k[r] = umin_(umin_(s2k[r], o2), umax_(s1k[r], o1));
            s1k[r] = umin_(s1k[r], o1);
        }
    }

    if (lane < 16) {                  // plain stores; one owner per (row, es)
        const int base = es * 16384;
#pragma unroll
        for (int r = 0; r < 4; r++) {
            k1q[base + (rt0 + r) * 16 + lane] = s1k[r];
            k2q[base + (rt0 + r) * 16 + lane] = s2k[r];
        }
    }
}

// ---- kernel 3: merge 16 partials; outputs; fp64 duel for near-ties -------
// Plane-major: thread t -> row n = t & 16383, channel quarter q = t >> 14.
__global__ __launch_bounds__(256) void vq_final(
        const float* __restrict__ z, const float* __restrict__ emb,
        const unsigned* __restrict__ k1q, const unsigned* __restrict__ k2q,
        float* __restrict__ out) {
    int t = blockIdx.x * 256 + threadIdx.x;   // 256 blocks x 256 = 65536
    int n = t & 16383;
    int q = t >> 14;

    unsigned m = 0xFFFFFFFFu, s = 0xFFFFFFFFu;
#pragma unroll
    for (int i = 0; i < 16; i++) {
        unsigned a = k1q[i * 16384 + n];
        unsigned b = k2q[i * 16384 + n];
        unsigned hi = umax_(m, a);
        m = umin_(m, a);
        s = umin_(umin_(s, b), hi);
    }

    int idx = (int)(m & 0xFFFu);
    float s1 = __uint_as_float(m & 0xFFFFF000u);
    float s2 = __uint_as_float(s & 0xFFFFF000u);

    int b = n >> 10, hw = n & 1023;
    const float* zp = z + (size_t)b * CHW_ + hw;
    const int cq = q * 16;

    if (s2 - s1 < EPS_GAP) {                   // near-tie: exact fp64 duel
        int i2 = (int)(s & 0xFFFu);
        const float* ea = emb + (size_t)idx * 64;
        const float* eb = emb + (size_t)i2 * 64;
        double da = 0.0, db = 0.0;
#pragma unroll 8
        for (int c = 0; c < 64; c++) {
            double zv = (double)zp[c * HW_];
            double xa = (double)ea[c] - zv;
            double xb = (double)eb[c] - zv;
            da = fma(xa, xa, da);
            db = fma(xb, xb, db);
        }
        if (db < da || (db == da && i2 < idx)) idx = i2;
    }

    const float* er = emb + (size_t)idx * 64 + cq;
    float* zq = out + (size_t)b * CHW_ + hw;
    float lsum = 0.f;
#pragma unroll
    for (int j = 0; j < 16; j++) {
        float e = er[j];
        float d = e - zp[(cq + j) * HW_];
        zq[(cq + j) * HW_] = e;
        lsum = fmaf(d, d, lsum);
    }
    if (q == 0) out[IDX_OFF + n] = (float)idx;

#pragma unroll
    for (int off = 32; off; off >>= 1) lsum += __shfl_down(lsum, off);
    if ((threadIdx.x & 63) == 0) atomicAdd(&out[LOSS_OFF], lsum * LOSS_SCALE);
}

extern "C" void kernel_launch(void* const* d_in, const int* in_sizes, int n_in,
                              void* d_out, int out_size, void* d_ws, size_t ws_size,
                              hipStream_t stream) {
    const float* z   = (const float*)d_in[0];
    const float* emb = (const float*)d_in[1];
    float* out = (float*)d_out;
    char* ws = (char*)d_ws;

    float* h_e    = (float*)ws;                       // 16 KB
    float* h_z    = (float*)(ws + 16384);             // 64 KB
    unsigned* k1q = (unsigned*)(ws + 81920);          // 1 MB (16 partials)
    unsigned* k2q = (unsigned*)(ws + 1130496);        // 1 MB
    char* zfrag   = ws + 2179072;                     // 4 MB
    char* efrag   = ws + 6373376;                     // 1 MB

    vq_pre  <<<720, 256, 0, stream>>>(z, emb, h_e, h_z, zfrag, efrag, out);
    vq_mfma <<<1024, 256, 0, stream>>>(zfrag, efrag, h_e, h_z, k1q, k2q);
    vq_final<<<256, 256, 0, stream>>>(z, emb, k1q, k2q, out);
}